// Round 6
// baseline (2170.494 us; speedup 1.0000x reference)
//
#include <hip/hip_runtime.h>

// DegModel: kernel-prediction net (17x conv3x3 + 1x1 conv to 441 taps) +
// tap-normalized spatially-varying 21x21 downsample (stride 4, reflect pad).
//
// fp64 conv chain (1/tap-sum amplification: fp32 chain fails 1280 > 1177;
// fp64 passes at 576). Round 6 = amortize the per-c-step scalar weight
// stall: each block computes TWO batches (same tile, same ocg) -> 144
// v_fma_f64 per weight fetch instead of 72. Round-5 evidence: 2x TLP
// (22->42% occupancy) left VALUBusy at 30% -> stall is per-wave serialized
// SGPR-limited weight fetch (72 doubles = 144 SGPR > budget), not hideable
// latency. Weights stay on the scalar pipe ([ocg][c][8oc*9] layout, round-4
// lesson: LDS weights = 155 GB LDS traffic; round-3 lesson: per-oc
// s_load_dwordx16 unpipelineable at SGPR=112).

#define NB 8        // batch
#define NF 64       // features
#define SP 4096     // 64*64 spatial
#define PS 66       // padded spatial dim
#define PS2 4356    // 66*66
#define K2 441      // 21*21 taps
#define K2P 448     // padded taps (7 chunks x 64)
#define RES_WSTRIDE (64*64*9)
#define RES_TSTRIDE (64*576)   // transformed per-layer stride (doubles)

// ---------------------------------------------------------------------------
__global__ void cvt_f32_to_f64(const float* __restrict__ src,
                               double* __restrict__ dst, int n)
{
    int i = blockIdx.x * blockDim.x + threadIdx.x;
    if (i < n) dst[i] = (double)src[i];
}

// z (8,3,64,64) fp32 -> zp (8,3,66,66) fp64 interior (borders pre-zeroed)
__global__ void prep_zpad(const float* __restrict__ z, double* __restrict__ zp)
{
    int i = blockIdx.x * blockDim.x + threadIdx.x;
    if (i >= NB * 3 * SP) return;
    int bc = i >> 12, p = i & 4095, y = p >> 6, x = p & 63;
    zp[(size_t)(bc * PS + y + 1) * PS + x + 1] = (double)z[i];
}

// conv weights OIHW fp32 -> [layer][ocg8][c][oc8][k9] fp64 (contiguous 72
// doubles per (ocg,c) = one c-step's scalar-load row).
__global__ void prep_convw(const float* __restrict__ src, double* __restrict__ dst,
                           int CIN, int nlayer, int wstride)
{
    int i = blockIdx.x * blockDim.x + threadIdx.x;
    int M = CIN * 576;                  // per-layer transformed count
    if (i >= nlayer * M) return;
    int l   = i / M;
    int r   = i - l * M;
    int ocg = r / (CIN * 72);
    int r2  = r - ocg * (CIN * 72);
    int c   = r2 / 72;
    int q   = r2 - c * 72;
    int oc  = q / 9;
    int k   = q - oc * 9;
    dst[i] = (double)src[l * wstride + ((ocg * 8 + oc) * CIN + c) * 9 + k];
}

// last_w (441,64) -> wT (64,448) fp64, zero-pad taps 441..447; pad bias.
__global__ void prep_lastw(const float* __restrict__ lw, const float* __restrict__ lb,
                           double* __restrict__ wT, double* __restrict__ bp)
{
    int i = blockIdx.x * blockDim.x + threadIdx.x;
    if (i < 64 * K2P) {
        int c = i / K2P, t = i - c * K2P;
        wT[i] = (t < K2) ? (double)lw[t * 64 + c] : 0.0;
    }
    if (i < K2P) bp[i] = (i < K2) ? (double)lb[i] : 0.0;
}

// ---------------------------------------------------------------------------
// conv3x3 fp64 on zero-padded NCHW (66x66). Block: 256 thr = 16x16 spatial
// tile, 8 oc/thread, TWO batches. Grid 512: bid = tile*32 + bp*8 + ocg (ocg
// fastest -> adjacent blocks share input tiles in L2). 2 blocks/CU.
// Input chunks staged async (global_load_lds 16B) into double-buffered LDS;
// weights via wave-uniform scalar loads from the transformed layout, each
// fetch feeding 144 FMAs (2 batches x 8 oc x 9 taps).
// ---------------------------------------------------------------------------
template<int CIN, int CCHUNK, bool RELU, bool RESADD>
__global__ __launch_bounds__(256, 2)
void conv3x3_kernel(const double* __restrict__ in, const double* __restrict__ wgtT,
                    const double* __restrict__ bias, const double* __restrict__ res,
                    double* __restrict__ out)
{
    constexpr int CP    = CCHUNK * 162;          // pairs per (batch, chunk)
    constexpr int NPAIR = 2 * CP;                // 16B pairs per staged chunk
    constexpr int NSTG  = (NPAIR + 255) / 256;   // full-wave staging iterations
    constexpr int PADP  = NSTG * 256;            // padded pair count (LDS slack)

    const int bid  = blockIdx.x;
    const int ocg  = bid & 7;                    // fastest
    const int b0   = ((bid >> 3) & 3) * 2;       // batch pair
    const int tile = bid >> 5;                   // 0..15
    const int i0   = (tile >> 2) << 4;
    const int j0   = (tile & 3) << 4;
    const int tid  = threadIdx.x;
    const int ti   = tid >> 4, tj = tid & 15;

    __shared__ double s_in[2][PADP * 2];

    const double* wbase = wgtT + (size_t)ocg * CIN * 72;

    double acc[2][8];
#pragma unroll
    for (int oc = 0; oc < 8; ++oc) {
        double bv = bias[ocg * 8 + oc];
        acc[0][oc] = bv;
        acc[1][oc] = bv;
    }

    auto stage = [&](int cb, int bf) {
#pragma unroll
        for (int k = 0; k < NSTG; ++k) {
            int e  = tid + k * 256;
            int e2 = (e < NPAIR) ? e : 0;        // clamp: slack lanes reload pair 0
            int b2 = e2 / CP;
            int rm = e2 - b2 * CP;
            int c  = rm / 162;
            int pr = rm - c * 162;
            int r  = pr / 9;
            int pc = pr - r * 9;
            const double* gp = in + (size_t)((b0 + b2) * CIN + cb + c) * PS2
                                  + (i0 + r) * PS + j0 + 2 * pc;
            __builtin_amdgcn_global_load_lds(
                (const __attribute__((address_space(1))) void*)gp,
                (__attribute__((address_space(3))) void*)&s_in[bf][e * 2],
                16, 0, 0);
        }
    };

    stage(0, 0);
    __syncthreads();                             // drains vmcnt before barrier

    int bf = 0;
    for (int cb = 0; cb < CIN; cb += CCHUNK) {
        if (cb + CCHUNK < CIN) stage(cb + CCHUNK, bf ^ 1);   // async prefetch
#pragma unroll
        for (int c = 0; c < CCHUNK; ++c) {
            const double* wrow = wbase + (size_t)(cb + c) * 72;  // uniform -> s_load
            const double* sc0  = &s_in[bf][c * 324];
            const double* sc1  = &s_in[bf][(CCHUNK + c) * 324];
            double v0[9], v1[9];
#pragma unroll
            for (int dy = 0; dy < 3; ++dy)
#pragma unroll
                for (int dx = 0; dx < 3; ++dx) {
                    v0[dy * 3 + dx] = sc0[(ti + dy) * 18 + tj + dx];
                    v1[dy * 3 + dx] = sc1[(ti + dy) * 18 + tj + dx];
                }
#pragma unroll
            for (int oc = 0; oc < 8; ++oc) {
                double a0 = acc[0][oc];
                double a1 = acc[1][oc];
#pragma unroll
                for (int k = 0; k < 9; ++k) {
                    double w = wrow[oc * 9 + k];
                    a0 = fma(w, v0[k], a0);
                    a1 = fma(w, v1[k], a1);
                }
                acc[0][oc] = a0;
                acc[1][oc] = a1;
            }
        }
        __syncthreads();                         // prefetch landed + reads done
        bf ^= 1;
    }

    const int pi = i0 + ti + 1, pj = j0 + tj + 1;
#pragma unroll
    for (int b2 = 0; b2 < 2; ++b2)
#pragma unroll
        for (int oc = 0; oc < 8; ++oc) {
            size_t idx = ((size_t)((b0 + b2) * NF + ocg * 8 + oc) * PS + pi) * PS + pj;
            double val = acc[b2][oc];
            if (RELU)   val = fmax(val, 0.0);
            if (RESADD) val += res[idx];
            out[idx] = val;
        }
}

// ---------------------------------------------------------------------------
// 1x1 conv h(64ch fp64, padded layout) -> 448 (441+pad) taps. Block = (b,
// 64-pos row), 256 thr: octet o = tid>>5 (8 taps), pos-pair pp = tid&31.
// h-row-tile (32 KB) staged once; 64-tap weight chunk (32 KB) per iteration.
// Raw taps stored fp32 (float2) into d_out kernel region; per-pos fp64
// tap-sum via deterministic LDS reduce. Grid: 8 b * 64 rows = 512 blocks.
// ---------------------------------------------------------------------------
__global__ __launch_bounds__(256, 2)
void lastconv_kernel(const double* __restrict__ hp, const double* __restrict__ wT,
                     const double* __restrict__ biasp, float* __restrict__ kraw,
                     double* __restrict__ sums)
{
    const int b   = blockIdx.x >> 6;
    const int row = blockIdx.x & 63;
    const int p0  = row << 6;
    const int tid = threadIdx.x;
    const int o   = tid >> 5;        // tap octet 0..7
    const int pp  = tid & 31;        // pos pair 0..31
    const int p   = pp * 2;
    const int o8  = o * 8;

    __shared__ double s_h[64][64];   // [c][pos]  32 KB
    __shared__ double s_w[64][64];   // [c][tap]  32 KB (per 64-tap chunk)
    __shared__ double s_red[8][64];  // 4 KB

    for (int e = tid; e < 4096; e += 256) {
        int c = e >> 6, q = e & 63;
        s_h[c][q] = hp[(size_t)(b * NF + c) * PS2 + (row + 1) * PS + 1 + q];
    }

    double sp0 = 0.0, sp1 = 0.0;

    for (int it = 0; it < 7; ++it) {
        __syncthreads();             // prev chunk compute done (covers s_h it=0)
        for (int e = tid; e < 4096; e += 256) {
            int c = e >> 6, t = e & 63;
            s_w[c][t] = wT[c * K2P + it * 64 + t];
        }
        __syncthreads();

        const int t0 = it * 64 + o8;
        double acc[8][2];
#pragma unroll
        for (int j = 0; j < 8; ++j) { acc[j][0] = biasp[t0 + j]; acc[j][1] = acc[j][0]; }

#pragma unroll 16
        for (int c = 0; c < 64; ++c) {
            double h0 = s_h[c][p];
            double h1 = s_h[c][p + 1];
#pragma unroll
            for (int j = 0; j < 8; ++j) {
                double w = s_w[c][o8 + j];
                acc[j][0] = fma(w, h0, acc[j][0]);
                acc[j][1] = fma(w, h1, acc[j][1]);
            }
        }

#pragma unroll
        for (int j = 0; j < 8; ++j) {
            int T = t0 + j;
            sp0 += acc[j][0];        // pad taps are exactly 0 (zero w+bias)
            sp1 += acc[j][1];
            if (T < K2) {
                float2 v = make_float2((float)acc[j][0], (float)acc[j][1]);
                *(float2*)&kraw[(size_t)(b * K2 + T) * SP + p0 + p] = v;
            }
        }
    }

    s_red[o][p]     = sp0;
    s_red[o][p + 1] = sp1;
    __syncthreads();
    if (tid < 64) {
        double s = 0.0;
#pragma unroll
        for (int oo = 0; oo < 8; ++oo) s += s_red[oo][tid];
        sums[b * SP + p0 + tid] = s;
    }
}

// ---------------------------------------------------------------------------
// Normalize kernel in place + apply to reflect-padded 21x21 patches of x.
// (numerics here are not 1/s-amplified, fp32 ok)
// ---------------------------------------------------------------------------
__global__ __launch_bounds__(256)
void apply_kernel(const float* __restrict__ x, const double* __restrict__ sums,
                  float* __restrict__ kout, float* __restrict__ out)
{
    const int bid  = blockIdx.x;
    const int g    = bid & 3;
    const int tile = (bid >> 2) & 15;
    const int b    = bid >> 6;
    const int i0   = (tile >> 2) << 4;
    const int j0   = (tile & 3) << 4;
    const int tid  = threadIdx.x;
    const int ti   = tid >> 4, tj = tid & 15;

    __shared__ float s_x[3][81][84];   // 81,648 B

    for (int e = tid; e < 3 * 81 * 84; e += 256) {
        int c   = e / 6804;
        int rem = e - c * 6804;
        int u   = rem / 84;
        int v   = rem - u * 84;
        int gr  = i0 * 4 + u - 10;
        int gc  = j0 * 4 + v - 10;
        gr = gr < 0 ? -gr : (gr > 255 ? 510 - gr : gr);
        gc = gc < 0 ? -gc : (gc > 255 ? 510 - gc : gc);
        int vp = (v & 3) * 21 + (v >> 2);
        s_x[c][u][vp] = x[((b * 3 + c) * 256 + gr) * 256 + gc];
    }
    __syncthreads();

    const int p = (i0 + ti) * 64 + (j0 + tj);
    const double inv = 1.0 / (sums[b * SP + p] + 1e-8);

    float o0 = 0.f, o1 = 0.f, o2 = 0.f;
    const int t0 = g * 111;
    const int t1 = (t0 + 111 < K2) ? t0 + 111 : K2;
    for (int t = t0; t < t1; ++t) {
        int ty = t / 21, tx = t - ty * 21;
        float* kp = &kout[(size_t)(b * K2 + t) * SP + p];
        float k  = *kp;
        float kn = (float)((double)k * inv);
        *kp = kn;
        int u  = ti * 4 + ty;
        int vp = (tx & 3) * 21 + tj + (tx >> 2);
        o0 = fmaf(s_x[0][u][vp], kn, o0);
        o1 = fmaf(s_x[1][u][vp], kn, o1);
        o2 = fmaf(s_x[2][u][vp], kn, o2);
    }
    atomicAdd(&out[(b * 3 + 0) * SP + p], o0);
    atomicAdd(&out[(b * 3 + 1) * SP + p], o1);
    atomicAdd(&out[(b * 3 + 2) * SP + p], o2);
}

// ---------------------------------------------------------------------------
extern "C" void kernel_launch(void* const* d_in, const int* in_sizes, int n_in,
                              void* d_out, int out_size, void* d_ws, size_t ws_size,
                              hipStream_t stream)
{
    (void)in_sizes; (void)n_in; (void)out_size; (void)ws_size;

    const float* x = (const float*)d_in[0];
    const float* z = (const float*)d_in[1];

    float* out  = (float*)d_out;                 // (8,3,64,64)
    float* kout = (float*)d_out + NB * 3 * SP;   // (8,441,64,64) raw -> normalized

    // ws layout (doubles)
    double* wd = (double*)d_ws;
    const int n_c0wT = 3 * 576;            // 1728
    const int n_rwT  = 8 * RES_TSTRIDE;    // 294912 each
    double* c0wT = wd;
    double* rwT1 = c0wT + n_c0wT;
    double* rwT2 = rwT1 + n_rwT;
    double* c0b  = rwT2 + n_rwT;
    double* rb1  = c0b + 64;
    double* rb2  = rb1 + 512;
    double* lwT  = rb2 + 512;              // 64*448
    double* lbp  = lwT + 64 * K2P;         // 448
    double* zp   = lbp + K2P;              // 8*3*66*66
    double* hp   = zp + NB * 3 * PS2;      // 8*64*66*66 = 17.8 MB
    double* tp   = hp + NB * NF * PS2;     // 17.8 MB
    double* sums = tp;                     // aliases tp (free after conv chain)

    // zero padded buffers (borders must be 0; interiors get overwritten)
    hipMemsetAsync(zp, 0, (size_t)NB * 3 * PS2 * sizeof(double), stream);
    hipMemsetAsync(hp, 0, (size_t)NB * NF * PS2 * sizeof(double), stream);
    hipMemsetAsync(tp, 0, (size_t)NB * NF * PS2 * sizeof(double), stream);
    hipMemsetAsync(out, 0, NB * 3 * SP * sizeof(float), stream);

    // weight prep
    prep_zpad<<<(NB * 3 * SP + 255) / 256, 256, 0, stream>>>(z, zp);
    prep_convw<<<(3 * 576 + 255) / 256, 256, 0, stream>>>(
        (const float*)d_in[2], c0wT, 3, 1, 0);
    prep_convw<<<(8 * 64 * 576 + 255) / 256, 256, 0, stream>>>(
        (const float*)d_in[4], rwT1, 64, 8, RES_WSTRIDE);
    prep_convw<<<(8 * 64 * 576 + 255) / 256, 256, 0, stream>>>(
        (const float*)d_in[6], rwT2, 64, 8, RES_WSTRIDE);
    cvt_f32_to_f64<<<1, 64,  0, stream>>>((const float*)d_in[3], c0b, 64);
    cvt_f32_to_f64<<<2, 256, 0, stream>>>((const float*)d_in[5], rb1, 512);
    cvt_f32_to_f64<<<2, 256, 0, stream>>>((const float*)d_in[7], rb2, 512);
    prep_lastw<<<(64 * K2P + 255) / 256, 256, 0, stream>>>(
        (const float*)d_in[8], (const float*)d_in[9], lwT, lbp);

    conv3x3_kernel<3, 3, false, false><<<512, 256, 0, stream>>>(zp, c0wT, c0b, nullptr, hp);
    for (int i = 0; i < 8; ++i) {
        conv3x3_kernel<64, 4, true,  false><<<512, 256, 0, stream>>>(
            hp, rwT1 + i * RES_TSTRIDE, rb1 + i * 64, nullptr, tp);
        conv3x3_kernel<64, 4, false, true ><<<512, 256, 0, stream>>>(
            tp, rwT2 + i * RES_TSTRIDE, rb2 + i * 64, hp, hp);
    }
    lastconv_kernel<<<512, 256, 0, stream>>>(hp, lwT, lbp, kout, sums);
    apply_kernel<<<512, 256, 0, stream>>>(x, sums, kout, out);
}

// Round 7
// 1946.608 us; speedup vs baseline: 1.1150x; 1.1150x over previous
//
#include <hip/hip_runtime.h>

// DegModel: kernel-prediction net (17x conv3x3 + 1x1 conv to 441 taps) +
// tap-normalized spatially-varying 21x21 downsample (stride 4, reflect pad).
//
// fp64 conv chain (1/tap-sum amplification: fp32 chain fails 1280 > 1177;
// fp64 passes at 576). Round 7 = contiguous staging. Evidence r4-r6: VALU
// busy-time always ~= fp64 FMA floor (31-39 us) while dur ~110-124 us and
// invariant to TLP (r5), FMA-per-weight-fetch (r6), and FETCH volume ->
// bottleneck is scattered-request staging latency (144B-used segments at
// 528B stride ~= 1 L2 miss per 16B request, MSHR-limited). Fix: block =
// 4 rows x 64 cols so the staged region per channel is 6 FULL padded rows
// = one contiguous 3168B span; requests collapse to ~50 dense 128B lines
// per chunk. Wave = one row -> stride-1 ds_read (free), 512B contiguous
// stores. Same math order -> bit-identical output (absmax 576).
//  - weights stay on scalar pipe ([ocg][c][8oc*9]); r3 lesson: per-oc
//    x16 s_loads unpipelineable; r4 lesson: LDS weights = 155 GB traffic.

#define NB 8        // batch
#define NF 64       // features
#define SP 4096     // 64*64 spatial
#define PS 66       // padded spatial dim
#define PS2 4356    // 66*66
#define K2 441      // 21*21 taps
#define K2P 448     // padded taps (7 chunks x 64)
#define RES_WSTRIDE (64*64*9)
#define RES_TSTRIDE (64*576)   // transformed per-layer stride (doubles)

// ---------------------------------------------------------------------------
__global__ void cvt_f32_to_f64(const float* __restrict__ src,
                               double* __restrict__ dst, int n)
{
    int i = blockIdx.x * blockDim.x + threadIdx.x;
    if (i < n) dst[i] = (double)src[i];
}

// z (8,3,64,64) fp32 -> zp (8,3,66,66) fp64 interior (borders pre-zeroed)
__global__ void prep_zpad(const float* __restrict__ z, double* __restrict__ zp)
{
    int i = blockIdx.x * blockDim.x + threadIdx.x;
    if (i >= NB * 3 * SP) return;
    int bc = i >> 12, p = i & 4095, y = p >> 6, x = p & 63;
    zp[(size_t)(bc * PS + y + 1) * PS + x + 1] = (double)z[i];
}

// conv weights OIHW fp32 -> [layer][ocg8][c][oc8][k9] fp64 (contiguous 72
// doubles per (ocg,c) = one c-step's scalar-load row).
__global__ void prep_convw(const float* __restrict__ src, double* __restrict__ dst,
                           int CIN, int nlayer, int wstride)
{
    int i = blockIdx.x * blockDim.x + threadIdx.x;
    int M = CIN * 576;                  // per-layer transformed count
    if (i >= nlayer * M) return;
    int l   = i / M;
    int r   = i - l * M;
    int ocg = r / (CIN * 72);
    int r2  = r - ocg * (CIN * 72);
    int c   = r2 / 72;
    int q   = r2 - c * 72;
    int oc  = q / 9;
    int k   = q - oc * 9;
    dst[i] = (double)src[l * wstride + ((ocg * 8 + oc) * CIN + c) * 9 + k];
}

// last_w (441,64) -> wT (64,448) fp64, zero-pad taps 441..447; pad bias.
__global__ void prep_lastw(const float* __restrict__ lw, const float* __restrict__ lb,
                           double* __restrict__ wT, double* __restrict__ bp)
{
    int i = blockIdx.x * blockDim.x + threadIdx.x;
    if (i < 64 * K2P) {
        int c = i / K2P, t = i - c * K2P;
        wT[i] = (t < K2) ? (double)lw[t * 64 + c] : 0.0;
    }
    if (i < K2P) bp[i] = (i < K2) ? (double)lb[i] : 0.0;
}

// ---------------------------------------------------------------------------
// conv3x3 fp64 on zero-padded NCHW (66x66). Block: 256 thr = 4 rows x 64
// cols (full width band), 8 oc/thread. Grid 1024: bid = band*64 + b*8 + ocg
// (ocg fastest; co-resident blocks bid+256k share ocg -> weight locality).
// 4 blocks/CU. Staged region per channel = 6 full padded rows = 3168 B
// CONTIGUOUS -> dense streaming global_load_lds (16B), double-buffered.
// Wave = one output row: stride-1 LDS reads (2-way alias = free), 512 B
// contiguous global stores. Weights via wave-uniform scalar loads.
// ---------------------------------------------------------------------------
template<int CIN, int CCHUNK, bool RELU, bool RESADD>
__global__ __launch_bounds__(256, 4)
void conv3x3_kernel(const double* __restrict__ in, const double* __restrict__ wgtT,
                    const double* __restrict__ bias, const double* __restrict__ res,
                    double* __restrict__ out)
{
    constexpr int CPAIR = 198;                   // 16B pairs per channel (6 rows x 66)
    constexpr int NPAIR = CCHUNK * CPAIR;
    constexpr int NSTG  = (NPAIR + 255) / 256;   // full-wave staging iterations
    constexpr int PADP  = NSTG * 256;            // padded pair count (clamp slack)

    const int bid  = blockIdx.x;
    const int ocg  = bid & 7;                    // fastest
    const int b    = (bid >> 3) & 7;
    const int band = bid >> 6;                   // 0..15 (4-row band)
    const int i0   = band * 4;                   // top halo padded row
    const int tid  = threadIdx.x;
    const int ti   = tid >> 6;                   // 0..3  (== wave id)
    const int tj   = tid & 63;

    __shared__ double s_in[2][PADP * 2];

    const double* wbase = wgtT + (size_t)ocg * CIN * 72;
    const double* gb    = in + (size_t)b * CIN * PS2 + (size_t)i0 * PS;

    double acc[8];
#pragma unroll
    for (int oc = 0; oc < 8; ++oc) acc[oc] = bias[ocg * 8 + oc];

    auto stage = [&](int cb, int bf) {
#pragma unroll
        for (int k = 0; k < NSTG; ++k) {
            int e  = tid + k * 256;
            int e2 = (e < NPAIR) ? e : 0;        // clamp: slack lanes reload pair 0
            int c  = e2 / CPAIR;
            int pr = e2 - c * CPAIR;             // pair within the 6-row span
            const double* gp = gb + (size_t)(cb + c) * PS2 + 2 * pr;
            __builtin_amdgcn_global_load_lds(
                (const __attribute__((address_space(1))) void*)gp,
                (__attribute__((address_space(3))) void*)&s_in[bf][e * 2],
                16, 0, 0);
        }
    };

    stage(0, 0);
    __syncthreads();                             // drains vmcnt before barrier

    int bf = 0;
    for (int cb = 0; cb < CIN; cb += CCHUNK) {
        if (cb + CCHUNK < CIN) stage(cb + CCHUNK, bf ^ 1);   // async prefetch
#pragma unroll
        for (int c = 0; c < CCHUNK; ++c) {
            const double* wrow = wbase + (size_t)(cb + c) * 72;  // uniform -> s_load
            const double* sc   = &s_in[bf][c * 396];             // 6 rows x 66
            double v[9];
#pragma unroll
            for (int dy = 0; dy < 3; ++dy)
#pragma unroll
                for (int dx = 0; dx < 3; ++dx)
                    v[dy * 3 + dx] = sc[(ti + dy) * PS + tj + dx];
#pragma unroll
            for (int oc = 0; oc < 8; ++oc) {
                double a = acc[oc];
#pragma unroll
                for (int k = 0; k < 9; ++k) a = fma(wrow[oc * 9 + k], v[k], a);
                acc[oc] = a;
            }
        }
        __syncthreads();                         // prefetch landed + reads done
        bf ^= 1;
    }

    const int pi = i0 + ti + 1, pj = tj + 1;
#pragma unroll
    for (int oc = 0; oc < 8; ++oc) {
        size_t idx = ((size_t)(b * NF + ocg * 8 + oc) * PS + pi) * PS + pj;
        double val = acc[oc];
        if (RELU)   val = fmax(val, 0.0);
        if (RESADD) val += res[idx];
        out[idx] = val;
    }
}

// ---------------------------------------------------------------------------
// 1x1 conv h(64ch fp64, padded layout) -> 448 (441+pad) taps. Block = (b,
// 64-pos row), 256 thr: octet o = tid>>5 (8 taps), pos-pair pp = tid&31.
// h-row-tile (32 KB) staged once; 64-tap weight chunk (32 KB) per iteration.
// Raw taps stored fp32 (float2) into d_out kernel region; per-pos fp64
// tap-sum via deterministic LDS reduce. Grid: 8 b * 64 rows = 512 blocks.
// ---------------------------------------------------------------------------
__global__ __launch_bounds__(256, 2)
void lastconv_kernel(const double* __restrict__ hp, const double* __restrict__ wT,
                     const double* __restrict__ biasp, float* __restrict__ kraw,
                     double* __restrict__ sums)
{
    const int b   = blockIdx.x >> 6;
    const int row = blockIdx.x & 63;
    const int p0  = row << 6;
    const int tid = threadIdx.x;
    const int o   = tid >> 5;        // tap octet 0..7
    const int pp  = tid & 31;        // pos pair 0..31
    const int p   = pp * 2;
    const int o8  = o * 8;

    __shared__ double s_h[64][64];   // [c][pos]  32 KB
    __shared__ double s_w[64][64];   // [c][tap]  32 KB (per 64-tap chunk)
    __shared__ double s_red[8][64];  // 4 KB

    for (int e = tid; e < 4096; e += 256) {
        int c = e >> 6, q = e & 63;
        s_h[c][q] = hp[(size_t)(b * NF + c) * PS2 + (row + 1) * PS + 1 + q];
    }

    double sp0 = 0.0, sp1 = 0.0;

    for (int it = 0; it < 7; ++it) {
        __syncthreads();             // prev chunk compute done (covers s_h it=0)
        for (int e = tid; e < 4096; e += 256) {
            int c = e >> 6, t = e & 63;
            s_w[c][t] = wT[c * K2P + it * 64 + t];
        }
        __syncthreads();

        const int t0 = it * 64 + o8;
        double acc[8][2];
#pragma unroll
        for (int j = 0; j < 8; ++j) { acc[j][0] = biasp[t0 + j]; acc[j][1] = acc[j][0]; }

#pragma unroll 16
        for (int c = 0; c < 64; ++c) {
            double h0 = s_h[c][p];
            double h1 = s_h[c][p + 1];
#pragma unroll
            for (int j = 0; j < 8; ++j) {
                double w = s_w[c][o8 + j];
                acc[j][0] = fma(w, h0, acc[j][0]);
                acc[j][1] = fma(w, h1, acc[j][1]);
            }
        }

#pragma unroll
        for (int j = 0; j < 8; ++j) {
            int T = t0 + j;
            sp0 += acc[j][0];        // pad taps are exactly 0 (zero w+bias)
            sp1 += acc[j][1];
            if (T < K2) {
                float2 v = make_float2((float)acc[j][0], (float)acc[j][1]);
                *(float2*)&kraw[(size_t)(b * K2 + T) * SP + p0 + p] = v;
            }
        }
    }

    s_red[o][p]     = sp0;
    s_red[o][p + 1] = sp1;
    __syncthreads();
    if (tid < 64) {
        double s = 0.0;
#pragma unroll
        for (int oo = 0; oo < 8; ++oo) s += s_red[oo][tid];
        sums[b * SP + p0 + tid] = s;
    }
}

// ---------------------------------------------------------------------------
// Normalize kernel in place + apply to reflect-padded 21x21 patches of x.
// (numerics here are not 1/s-amplified, fp32 ok)
// ---------------------------------------------------------------------------
__global__ __launch_bounds__(256)
void apply_kernel(const float* __restrict__ x, const double* __restrict__ sums,
                  float* __restrict__ kout, float* __restrict__ out)
{
    const int bid  = blockIdx.x;
    const int g    = bid & 3;
    const int tile = (bid >> 2) & 15;
    const int b    = bid >> 6;
    const int i0   = (tile >> 2) << 4;
    const int j0   = (tile & 3) << 4;
    const int tid  = threadIdx.x;
    const int ti   = tid >> 4, tj = tid & 15;

    __shared__ float s_x[3][81][84];   // 81,648 B

    for (int e = tid; e < 3 * 81 * 84; e += 256) {
        int c   = e / 6804;
        int rem = e - c * 6804;
        int u   = rem / 84;
        int v   = rem - u * 84;
        int gr  = i0 * 4 + u - 10;
        int gc  = j0 * 4 + v - 10;
        gr = gr < 0 ? -gr : (gr > 255 ? 510 - gr : gr);
        gc = gc < 0 ? -gc : (gc > 255 ? 510 - gc : gc);
        int vp = (v & 3) * 21 + (v >> 2);
        s_x[c][u][vp] = x[((b * 3 + c) * 256 + gr) * 256 + gc];
    }
    __syncthreads();

    const int p = (i0 + ti) * 64 + (j0 + tj);
    const double inv = 1.0 / (sums[b * SP + p] + 1e-8);

    float o0 = 0.f, o1 = 0.f, o2 = 0.f;
    const int t0 = g * 111;
    const int t1 = (t0 + 111 < K2) ? t0 + 111 : K2;
    for (int t = t0; t < t1; ++t) {
        int ty = t / 21, tx = t - ty * 21;
        float* kp = &kout[(size_t)(b * K2 + t) * SP + p];
        float k  = *kp;
        float kn = (float)((double)k * inv);
        *kp = kn;
        int u  = ti * 4 + ty;
        int vp = (tx & 3) * 21 + tj + (tx >> 2);
        o0 = fmaf(s_x[0][u][vp], kn, o0);
        o1 = fmaf(s_x[1][u][vp], kn, o1);
        o2 = fmaf(s_x[2][u][vp], kn, o2);
    }
    atomicAdd(&out[(b * 3 + 0) * SP + p], o0);
    atomicAdd(&out[(b * 3 + 1) * SP + p], o1);
    atomicAdd(&out[(b * 3 + 2) * SP + p], o2);
}

// ---------------------------------------------------------------------------
extern "C" void kernel_launch(void* const* d_in, const int* in_sizes, int n_in,
                              void* d_out, int out_size, void* d_ws, size_t ws_size,
                              hipStream_t stream)
{
    (void)in_sizes; (void)n_in; (void)out_size; (void)ws_size;

    const float* x = (const float*)d_in[0];
    const float* z = (const float*)d_in[1];

    float* out  = (float*)d_out;                 // (8,3,64,64)
    float* kout = (float*)d_out + NB * 3 * SP;   // (8,441,64,64) raw -> normalized

    // ws layout (doubles)
    double* wd = (double*)d_ws;
    const int n_c0wT = 3 * 576;            // 1728
    const int n_rwT  = 8 * RES_TSTRIDE;    // 294912 each
    double* c0wT = wd;
    double* rwT1 = c0wT + n_c0wT;
    double* rwT2 = rwT1 + n_rwT;
    double* c0b  = rwT2 + n_rwT;
    double* rb1  = c0b + 64;
    double* rb2  = rb1 + 512;
    double* lwT  = rb2 + 512;              // 64*448
    double* lbp  = lwT + 64 * K2P;         // 448
    double* zp   = lbp + K2P;              // 8*3*66*66
    double* hp   = zp + NB * 3 * PS2;      // 8*64*66*66 = 17.8 MB
    double* tp   = hp + NB * NF * PS2;     // 17.8 MB
    double* sums = tp;                     // aliases tp (free after conv chain)

    // zero padded buffers (borders must be 0; interiors get overwritten)
    hipMemsetAsync(zp, 0, (size_t)NB * 3 * PS2 * sizeof(double), stream);
    hipMemsetAsync(hp, 0, (size_t)NB * NF * PS2 * sizeof(double), stream);
    hipMemsetAsync(tp, 0, (size_t)NB * NF * PS2 * sizeof(double), stream);
    hipMemsetAsync(out, 0, NB * 3 * SP * sizeof(float), stream);

    // weight prep
    prep_zpad<<<(NB * 3 * SP + 255) / 256, 256, 0, stream>>>(z, zp);
    prep_convw<<<(3 * 576 + 255) / 256, 256, 0, stream>>>(
        (const float*)d_in[2], c0wT, 3, 1, 0);
    prep_convw<<<(8 * 64 * 576 + 255) / 256, 256, 0, stream>>>(
        (const float*)d_in[4], rwT1, 64, 8, RES_WSTRIDE);
    prep_convw<<<(8 * 64 * 576 + 255) / 256, 256, 0, stream>>>(
        (const float*)d_in[6], rwT2, 64, 8, RES_WSTRIDE);
    cvt_f32_to_f64<<<1, 64,  0, stream>>>((const float*)d_in[3], c0b, 64);
    cvt_f32_to_f64<<<2, 256, 0, stream>>>((const float*)d_in[5], rb1, 512);
    cvt_f32_to_f64<<<2, 256, 0, stream>>>((const float*)d_in[7], rb2, 512);
    prep_lastw<<<(64 * K2P + 255) / 256, 256, 0, stream>>>(
        (const float*)d_in[8], (const float*)d_in[9], lwT, lbp);

    conv3x3_kernel<3, 3, false, false><<<1024, 256, 0, stream>>>(zp, c0wT, c0b, nullptr, hp);
    for (int i = 0; i < 8; ++i) {
        conv3x3_kernel<64, 4, true,  false><<<1024, 256, 0, stream>>>(
            hp, rwT1 + i * RES_TSTRIDE, rb1 + i * 64, nullptr, tp);
        conv3x3_kernel<64, 4, false, true ><<<1024, 256, 0, stream>>>(
            tp, rwT2 + i * RES_TSTRIDE, rb2 + i * 64, hp, hp);
    }
    lastconv_kernel<<<512, 256, 0, stream>>>(hp, lwT, lbp, kout, sums);
    apply_kernel<<<512, 256, 0, stream>>>(x, sums, kout, out);
}

// Round 9
// 1245.500 us; speedup vs baseline: 1.7427x; 1.5629x over previous
//
#include <hip/hip_runtime.h>

// DegModel: kernel-prediction net (17x conv3x3 + 1x1 conv to 441 taps) +
// tap-normalized spatially-varying 21x21 downsample (stride 4, reflect pad).
//
// fp64 conv chain (1/tap-sum amplification: fp32 chain fails 1280 > 1177;
// fp64 passes at 576). Round 9 = fp64 MFMA GEMM conv with ON-DEVICE
// LAYOUT PROBING. r8 failed (absmax 82k) on assumed v_mfma_f64_16x16x4
// fragment maps; no HW-verified f64 map exists. Fix: 1-wave probe kernel
// computes D1=mfma(lane,1,0) (A-rowsums -> row index per D element, and
// A-layout flag via mod-4: lane=i+16k rowsum=96+4i (=0 mod4) vs lane=4i+k
// rowsum=6+16i (=2 mod4)) and D2=mfma(1,lane,0) (B-colsums -> col index +
// B-layout flag). Decode kernel writes index tables (A lane->(i,k),
// B lane->(k,j), D (lane,reg)->(i,j)) to ws; weight/bias prep and the conv
// kernel are table-driven -> correct under any candidate layout.
// Rationale for MFMA (r4-r7): vector-fp64 conv pinned at VALUBusy ~31%,
// 110 us/layer across 4 staging designs -- the wave-uniform weight operand
// (8 B/FMA) cannot be fed by the scalar pipe. MFMA takes both operands
// from per-lane VGPRs via coalesced loads, 16 MACs/lane/instr.

#define NB 8        // batch
#define NF 64       // features
#define SP 4096     // 64*64 spatial
#define PS 66       // padded spatial dim
#define PS2 4356    // 66*66
#define K2 441      // 21*21 taps
#define K2P 448     // padded taps (7 chunks x 64)
#define RES_WSTRIDE (64*64*9)
#define WF_RES 49152           // per-layer fragment weights: 64c*3ph*4mt*64
#define WF_C0  2304            // 3c*3ph*4mt*64

typedef double vdbl4 __attribute__((ext_vector_type(4)));

// table offsets (ints) within the tabs block
#define T_AI 0      // [64]  A: lane -> i
#define T_AK 64     // [64]  A: lane -> k
#define T_BK 128    // [64]  B: lane -> k
#define T_BJ 192    // [64]  B: lane -> j
#define T_DI 256    // [256] D: r*64+l -> i
#define T_DJ 512    // [256] D: r*64+l -> j

// ---------------------------------------------------------------------------
// layout probe: one wave. D1[l,r] = rowsumA(i(l,r)), D2[l,r] = colsumB(j(l,r))
__global__ void probe_mfma(double* __restrict__ probe)
{
    int l = threadIdx.x;
    vdbl4 z = {0.0, 0.0, 0.0, 0.0};
    vdbl4 r1 = __builtin_amdgcn_mfma_f64_16x16x4f64((double)l, 1.0, z, 0, 0, 0);
    vdbl4 r2 = __builtin_amdgcn_mfma_f64_16x16x4f64(1.0, (double)l, z, 0, 0, 0);
#pragma unroll
    for (int r = 0; r < 4; ++r) {
        probe[r * 64 + l]       = r1[r];
        probe[256 + r * 64 + l] = r2[r];
    }
}

__global__ void decode_probe(const double* __restrict__ probe, int* __restrict__ tabs)
{
    int t = threadIdx.x;                 // 0..255
    const double* d1 = probe;
    const double* d2 = probe + 256;
    // layout flags: lane=i+16k => rowsum=96+4i (mod4==0); lane=4i+k => 6+16i (mod4==2)
    bool fA = ((((int)d1[0]) & 3) == 0);
    bool fB = ((((int)d2[0]) & 3) == 0);
    int v1 = (int)d1[t], v2 = (int)d2[t];
    tabs[T_DI + t] = fA ? (v1 - 96) >> 2 : (v1 - 6) >> 4;
    tabs[T_DJ + t] = fB ? (v2 - 96) >> 2 : (v2 - 6) >> 4;
    if (t < 64) {
        tabs[T_AI + t] = fA ? (t & 15) : (t >> 2);
        tabs[T_AK + t] = fA ? (t >> 4) : (t & 3);
        tabs[T_BK + t] = fB ? (t >> 4) : (t & 3);
        tabs[T_BJ + t] = fB ? (t & 15) : (t >> 2);
    }
}

// ---------------------------------------------------------------------------
// z (8,3,64,64) fp32 -> zp (8,3,66,66) fp64 interior (borders pre-zeroed)
__global__ void prep_zpad(const float* __restrict__ z, double* __restrict__ zp)
{
    int i = blockIdx.x * blockDim.x + threadIdx.x;
    if (i >= NB * 3 * SP) return;
    int bc = i >> 12, p = i & 4095, y = p >> 6, x = p & 63;
    zp[(size_t)(bc * PS + y + 1) * PS + x + 1] = (double)z[i];
}

// conv weights OIHW fp32 -> MFMA A-fragment order (table-driven), fp64:
// WF[layer][t4=(c*3+ph)][mt][lane] = W[oc=mt*16+Ai(l)][c][tap=ph*4+Ak(l)]
// (tap>8 -> 0.0 zero-pad).
__global__ void prep_convw_frag(const float* __restrict__ src, double* __restrict__ dst,
                                const int* __restrict__ tabs,
                                int CIN, int nlayer, int wstride)
{
    int i = blockIdx.x * blockDim.x + threadIdx.x;
    int M = CIN * 768;                   // CIN*3*4*64 per layer
    if (i >= nlayer * M) return;
    int li  = i / M;
    int rem = i - li * M;
    int t4  = rem >> 8;
    int j   = rem & 255;
    int mt  = j >> 6;
    int l   = j & 63;
    int c   = t4 / 3;
    int ph  = t4 - c * 3;
    int oc  = mt * 16 + tabs[T_AI + l];
    int tap = ph * 4 + tabs[T_AK + l];
    dst[i] = (tap < 9) ? (double)src[li * wstride + (oc * CIN + c) * 9 + tap] : 0.0;
}

// bias fp32 -> C-fragment order fp64 (table-driven):
// BF[layer][(mt*4+r)*64+lane] = bias[mt*16 + Di(r,l)]
__global__ void prep_bias_frag(const float* __restrict__ src, double* __restrict__ dst,
                               const int* __restrict__ tabs, int nlayer)
{
    int i = blockIdx.x * blockDim.x + threadIdx.x;
    if (i >= nlayer * 1024) return;
    int li  = i >> 10;
    int j   = i & 1023;
    int mtr = j >> 6;
    int l   = j & 63;
    int mt  = mtr >> 2, r = mtr & 3;
    dst[i] = (double)src[li * 64 + mt * 16 + tabs[T_DI + r * 64 + l]];
}

// last_w (441,64) -> wT (64,448) fp64, zero-pad taps 441..447; pad bias.
__global__ void prep_lastw(const float* __restrict__ lw, const float* __restrict__ lb,
                           double* __restrict__ wT, double* __restrict__ bp)
{
    int i = blockIdx.x * blockDim.x + threadIdx.x;
    if (i < 64 * K2P) {
        int c = i / K2P, t = i - c * K2P;
        wT[i] = (t < K2) ? (double)lw[t * 64 + c] : 0.0;
    }
    if (i < K2P) bp[i] = (i < K2) ? (double)lb[i] : 0.0;
}

// ---------------------------------------------------------------------------
// conv3x3 as fp64 MFMA GEMM: D(64oc x 64pos) = WF(64 x CIN*12) * P + bias.
// Block = 4 waves = one output row (b, y0); wave(mi,ni) owns the 32x32
// quadrant (mt = 2mi..2mi+1, nt = 2ni..2ni+1). P read straight from the
// zero-padded input via table-driven per-lane (k->tap, j) offsets.
// A-fragments are coalesced 512B loads from WF (L2-resident, shared by all
// blocks). 1-step software-pipelined preload. Grid 512 (= y0*8+b), 2/CU.
// No LDS, no __syncthreads.
// ---------------------------------------------------------------------------
template<int CIN, bool RELU, bool RESADD>
__global__ __launch_bounds__(256, 2)
void conv3x3_mfma(const double* __restrict__ in, const double* __restrict__ WF,
                  const double* __restrict__ BF, const int* __restrict__ tabs,
                  const double* __restrict__ res, double* __restrict__ out)
{
    const int bid = blockIdx.x;
    const int b   = bid & 7;
    const int y0  = bid >> 3;          // output row 0..63
    const int tid = threadIdx.x;
    const int w   = tid >> 6;
    const int l   = tid & 63;
    const int mi  = w >> 1, ni = w & 1;
    const int mt0 = mi * 2, nt0 = ni * 2;

    const int kB = tabs[T_BK + l];
    const int jB = tabs[T_BJ + l];

    // per-lane P offsets for the 3 tap-phases (pad taps alias tap 8)
    int offp[3];
#pragma unroll
    for (int ph = 0; ph < 3; ++ph) {
        int tap = ph * 4 + kB;
        if (tap > 8) tap = 8;          // weight is 0 there; just needs a valid addr
        int dy = tap / 3, dx = tap - dy * 3;
        offp[ph] = dy * PS + dx + jB;
    }

    const double* bbase = in + (size_t)b * CIN * PS2 + (size_t)y0 * PS;
    const double* wp    = WF;          // advances 256 doubles per K-step

    vdbl4 acc[2][2];
#pragma unroll
    for (int mt = 0; mt < 2; ++mt)
#pragma unroll
        for (int r = 0; r < 4; ++r) {
            double bv = BF[((mt0 + mt) * 4 + r) * 64 + l];
            acc[mt][0][r] = bv;
            acc[mt][1][r] = bv;
        }

    // preload K-step 0
    double a0 = wp[mt0 * 64 + l];
    double a1 = wp[(mt0 + 1) * 64 + l];
    double b0 = bbase[offp[0] + nt0 * 16];
    double b1 = bbase[offp[0] + nt0 * 16 + 16];

    for (int c = 0; c < CIN; ++c) {
#pragma unroll
        for (int ph = 0; ph < 3; ++ph) {
            double na0 = 0.0, na1 = 0.0, nb0 = 0.0, nb1 = 0.0;
            if (!(c == CIN - 1 && ph == 2)) {
                const double* nwp = wp + 256;
                const double* nbb = (ph == 2) ? bbase + PS2 : bbase;
                const int    nph  = (ph == 2) ? 0 : ph + 1;
                na0 = nwp[mt0 * 64 + l];
                na1 = nwp[(mt0 + 1) * 64 + l];
                nb0 = nbb[offp[nph] + nt0 * 16];
                nb1 = nbb[offp[nph] + nt0 * 16 + 16];
            }
            acc[0][0] = __builtin_amdgcn_mfma_f64_16x16x4f64(a0, b0, acc[0][0], 0, 0, 0);
            acc[0][1] = __builtin_amdgcn_mfma_f64_16x16x4f64(a0, b1, acc[0][1], 0, 0, 0);
            acc[1][0] = __builtin_amdgcn_mfma_f64_16x16x4f64(a1, b0, acc[1][0], 0, 0, 0);
            acc[1][1] = __builtin_amdgcn_mfma_f64_16x16x4f64(a1, b1, acc[1][1], 0, 0, 0);
            a0 = na0; a1 = na1; b0 = nb0; b1 = nb1;
            wp += 256;
        }
        bbase += PS2;
    }

    // epilogue: D element (i,j) per (lane, reg) from probe tables
    int iD[4], jD[4];
#pragma unroll
    for (int r = 0; r < 4; ++r) {
        iD[r] = tabs[T_DI + r * 64 + l];
        jD[r] = tabs[T_DJ + r * 64 + l];
    }
#pragma unroll
    for (int mt = 0; mt < 2; ++mt)
#pragma unroll
        for (int nt = 0; nt < 2; ++nt)
#pragma unroll
            for (int r = 0; r < 4; ++r) {
                int oc = (mt0 + mt) * 16 + iD[r];
                int x  = (nt0 + nt) * 16 + jD[r];
                size_t idx = (size_t)(b * NF + oc) * PS2 + (size_t)(y0 + 1) * PS + x + 1;
                double val = acc[mt][nt][r];
                if (RELU)   val = fmax(val, 0.0);
                if (RESADD) val += res[idx];
                out[idx] = val;
            }
}

// ---------------------------------------------------------------------------
// 1x1 conv h(64ch fp64, padded layout) -> 448 (441+pad) taps. (unchanged)
// ---------------------------------------------------------------------------
__global__ __launch_bounds__(256, 2)
void lastconv_kernel(const double* __restrict__ hp, const double* __restrict__ wT,
                     const double* __restrict__ biasp, float* __restrict__ kraw,
                     double* __restrict__ sums)
{
    const int b   = blockIdx.x >> 6;
    const int row = blockIdx.x & 63;
    const int p0  = row << 6;
    const int tid = threadIdx.x;
    const int o   = tid >> 5;
    const int pp  = tid & 31;
    const int p   = pp * 2;
    const int o8  = o * 8;

    __shared__ double s_h[64][64];
    __shared__ double s_w[64][64];
    __shared__ double s_red[8][64];

    for (int e = tid; e < 4096; e += 256) {
        int c = e >> 6, qq = e & 63;
        s_h[c][qq] = hp[(size_t)(b * NF + c) * PS2 + (row + 1) * PS + 1 + qq];
    }

    double sp0 = 0.0, sp1 = 0.0;

    for (int it = 0; it < 7; ++it) {
        __syncthreads();
        for (int e = tid; e < 4096; e += 256) {
            int c = e >> 6, t = e & 63;
            s_w[c][t] = wT[c * K2P + it * 64 + t];
        }
        __syncthreads();

        const int t0 = it * 64 + o8;
        double acc[8][2];
#pragma unroll
        for (int j = 0; j < 8; ++j) { acc[j][0] = biasp[t0 + j]; acc[j][1] = acc[j][0]; }

#pragma unroll 16
        for (int c = 0; c < 64; ++c) {
            double h0 = s_h[c][p];
            double h1 = s_h[c][p + 1];
#pragma unroll
            for (int j = 0; j < 8; ++j) {
                double wv = s_w[c][o8 + j];
                acc[j][0] = fma(wv, h0, acc[j][0]);
                acc[j][1] = fma(wv, h1, acc[j][1]);
            }
        }

#pragma unroll
        for (int j = 0; j < 8; ++j) {
            int T = t0 + j;
            sp0 += acc[j][0];
            sp1 += acc[j][1];
            if (T < K2) {
                float2 v = make_float2((float)acc[j][0], (float)acc[j][1]);
                *(float2*)&kraw[(size_t)(b * K2 + T) * SP + p0 + p] = v;
            }
        }
    }

    s_red[o][p]     = sp0;
    s_red[o][p + 1] = sp1;
    __syncthreads();
    if (tid < 64) {
        double s = 0.0;
#pragma unroll
        for (int oo = 0; oo < 8; ++oo) s += s_red[oo][tid];
        sums[b * SP + p0 + tid] = s;
    }
}

// ---------------------------------------------------------------------------
// Normalize kernel in place + apply to reflect-padded 21x21 patches of x.
// (unchanged — numerics here are not 1/s-amplified, fp32 ok)
// ---------------------------------------------------------------------------
__global__ __launch_bounds__(256)
void apply_kernel(const float* __restrict__ x, const double* __restrict__ sums,
                  float* __restrict__ kout, float* __restrict__ out)
{
    const int bid  = blockIdx.x;
    const int g    = bid & 3;
    const int tile = (bid >> 2) & 15;
    const int b    = bid >> 6;
    const int i0   = (tile >> 2) << 4;
    const int j0   = (tile & 3) << 4;
    const int tid  = threadIdx.x;
    const int ti   = tid >> 4, tj = tid & 15;

    __shared__ float s_x[3][81][84];

    for (int e = tid; e < 3 * 81 * 84; e += 256) {
        int c   = e / 6804;
        int rem = e - c * 6804;
        int u   = rem / 84;
        int v   = rem - u * 84;
        int gr  = i0 * 4 + u - 10;
        int gc  = j0 * 4 + v - 10;
        gr = gr < 0 ? -gr : (gr > 255 ? 510 - gr : gr);
        gc = gc < 0 ? -gc : (gc > 255 ? 510 - gc : gc);
        int vp = (v & 3) * 21 + (v >> 2);
        s_x[c][u][vp] = x[((b * 3 + c) * 256 + gr) * 256 + gc];
    }
    __syncthreads();

    const int p = (i0 + ti) * 64 + (j0 + tj);
    const double inv = 1.0 / (sums[b * SP + p] + 1e-8);

    float o0 = 0.f, o1 = 0.f, o2 = 0.f;
    const int t0 = g * 111;
    const int t1 = (t0 + 111 < K2) ? t0 + 111 : K2;
    for (int t = t0; t < t1; ++t) {
        int ty = t / 21, tx = t - ty * 21;
        float* kp = &kout[(size_t)(b * K2 + t) * SP + p];
        float k  = *kp;
        float kn = (float)((double)k * inv);
        *kp = kn;
        int u  = ti * 4 + ty;
        int vp = (tx & 3) * 21 + tj + (tx >> 2);
        o0 = fmaf(s_x[0][u][vp], kn, o0);
        o1 = fmaf(s_x[1][u][vp], kn, o1);
        o2 = fmaf(s_x[2][u][vp], kn, o2);
    }
    atomicAdd(&out[(b * 3 + 0) * SP + p], o0);
    atomicAdd(&out[(b * 3 + 1) * SP + p], o1);
    atomicAdd(&out[(b * 3 + 2) * SP + p], o2);
}

// ---------------------------------------------------------------------------
extern "C" void kernel_launch(void* const* d_in, const int* in_sizes, int n_in,
                              void* d_out, int out_size, void* d_ws, size_t ws_size,
                              hipStream_t stream)
{
    (void)in_sizes; (void)n_in; (void)out_size; (void)ws_size;

    const float* x = (const float*)d_in[0];
    const float* z = (const float*)d_in[1];

    float* out  = (float*)d_out;                 // (8,3,64,64)
    float* kout = (float*)d_out + NB * 3 * SP;   // (8,441,64,64) raw -> normalized

    // ws layout (doubles)
    double* wd    = (double*)d_ws;
    double* probe = wd;                      // 512 (D1, D2)
    int*    tabs  = (int*)(wd + 512);        // 1024 ints (=512 doubles w/ pad)
    double* wf0   = wd + 1024;               // 2304
    double* wf1   = wf0 + WF_C0;             // 8*49152
    double* wf2   = wf1 + 8 * WF_RES;        // 8*49152
    double* bf0   = wf2 + 8 * WF_RES;        // 1024
    double* bf1   = bf0 + 1024;              // 8*1024
    double* bf2   = bf1 + 8 * 1024;          // 8*1024
    double* lwT   = bf2 + 8 * 1024;          // 64*448
    double* lbp   = lwT + 64 * K2P;          // 448
    double* zp    = lbp + K2P;               // 8*3*66*66
    double* hp    = zp + NB * 3 * PS2;       // 8*64*66*66 = 17.8 MB
    double* tp    = hp + NB * NF * PS2;      // 17.8 MB
    double* sums  = tp;                      // aliases tp (free after conv chain)

    // zero padded buffers (borders must be 0; interiors get overwritten)
    hipMemsetAsync(zp, 0, (size_t)NB * 3 * PS2 * sizeof(double), stream);
    hipMemsetAsync(hp, 0, (size_t)NB * NF * PS2 * sizeof(double), stream);
    hipMemsetAsync(tp, 0, (size_t)NB * NF * PS2 * sizeof(double), stream);
    hipMemsetAsync(out, 0, NB * 3 * SP * sizeof(float), stream);

    // layout probe, then table-driven prep
    probe_mfma<<<1, 64, 0, stream>>>(probe);
    decode_probe<<<1, 256, 0, stream>>>(probe, tabs);

    prep_zpad<<<(NB * 3 * SP + 255) / 256, 256, 0, stream>>>(z, zp);
    prep_convw_frag<<<(WF_C0 + 255) / 256, 256, 0, stream>>>(
        (const float*)d_in[2], wf0, tabs, 3, 1, 0);
    prep_convw_frag<<<(8 * WF_RES + 255) / 256, 256, 0, stream>>>(
        (const float*)d_in[4], wf1, tabs, 64, 8, RES_WSTRIDE);
    prep_convw_frag<<<(8 * WF_RES + 255) / 256, 256, 0, stream>>>(
        (const float*)d_in[6], wf2, tabs, 64, 8, RES_WSTRIDE);
    prep_bias_frag<<<(1024 + 255) / 256, 256, 0, stream>>>(
        (const float*)d_in[3], bf0, tabs, 1);
    prep_bias_frag<<<(8 * 1024 + 255) / 256, 256, 0, stream>>>(
        (const float*)d_in[5], bf1, tabs, 8);
    prep_bias_frag<<<(8 * 1024 + 255) / 256, 256, 0, stream>>>(
        (const float*)d_in[7], bf2, tabs, 8);
    prep_lastw<<<(64 * K2P + 255) / 256, 256, 0, stream>>>(
        (const float*)d_in[8], (const float*)d_in[9], lwT, lbp);

    conv3x3_mfma<3,  false, false><<<512, 256, 0, stream>>>(zp, wf0, bf0, tabs, nullptr, hp);
    for (int i = 0; i < 8; ++i) {
        conv3x3_mfma<64, true,  false><<<512, 256, 0, stream>>>(
            hp, wf1 + i * WF_RES, bf1 + i * 1024, tabs, nullptr, tp);
        conv3x3_mfma<64, false, true ><<<512, 256, 0, stream>>>(
            tp, wf2 + i * WF_RES, bf2 + i * 1024, tabs, hp, hp);
    }
    lastconv_kernel<<<512, 256, 0, stream>>>(hp, lwT, lbp, kout, sums);
    apply_kernel<<<512, 256, 0, stream>>>(x, sums, kout, out);
}